// Round 3
// baseline (179.257 us; speedup 1.0000x reference)
//
#include <hip/hip_runtime.h>
#include <hip/hip_bf16.h>

#define MPTS 50000
#define NPTS 100000
#define KK 15
#define TM 16      // queries per tile; 8 waves, wave owns 2 -> barrier-free A/B phases
#define NTILES (MPTS / TM)              // 3125
#define TPB 4                           // tiles per persistent block (pipeline depth)
#define GRID ((NTILES + TPB - 1) / TPB) // 782
#define WTP 1028   // wtw row stride (shorts): 514 b32 = 2 mod 32 -> phase-C A reads uniform banks
#define STP 36     // weight-row stride inside wtw (shorts)
#define STPH 20    // half-h stage row stride (shorts): 40 B rows (8B-aligned)

typedef __attribute__((ext_vector_type(8))) short short8;
typedef __attribute__((ext_vector_type(4))) short short4v;
typedef __attribute__((ext_vector_type(4))) float floatx4;

static __device__ __forceinline__ unsigned short f2bf(float f) {
    __hip_bfloat16 h = __float2bfloat16(f);
    return *reinterpret_cast<unsigned short*>(&h);
}

static __device__ __forceinline__ short8 lds_load8(const unsigned short* p) {
    const short4v a = *(const short4v*)p;
    const short4v b = *(const short4v*)(p + 4);
    short8 r;
    r[0] = a[0]; r[1] = a[1]; r[2] = a[2]; r[3] = a[3];
    r[4] = b[0]; r[5] = b[1]; r[6] = b[2]; r[7] = b[3];
    return r;
}

// ===================== single prep kernel (3 jobs by blockIdx range) ==================
// [0,782):   one pass over s_feats rows -> sfb (bf16) + rowsum-sign packed with xyz into spts4
// [782,814): wbf2 lane-linear B frags (128 KB)
// 814:       tail: zero sfb row N, spts4[N]=(1e6,1e6,1e6,-1), kpp
__global__ void prep_all(const float* __restrict__ sf, const float* __restrict__ w,
                         const float* __restrict__ kpts, const float* __restrict__ spt,
                         unsigned short* __restrict__ sfb, float4* __restrict__ spts4,
                         unsigned short* __restrict__ wbf2, float4* __restrict__ kpp) {
    const int b = blockIdx.x, t = threadIdx.x;
    if (b < 782) {
        const int tt = b * 256 + t;
        const int row = tt >> 1, p = tt & 1;          // lane p covers cols 4p+8i+0..3
        if (row < NPTS) {
            const float* base = sf + (size_t)row * 64 + p * 4;
            float4 r = *(const float4*)base;          // i = 0
            {
                ushort4 o;
                o.x = f2bf(r.x); o.y = f2bf(r.y); o.z = f2bf(r.z); o.w = f2bf(r.w);
                *(ushort4*)&sfb[(size_t)row * 64 + p * 4] = o;
            }
#pragma unroll
            for (int i = 1; i < 8; i++) {
                const float4 x = *(const float4*)(base + i * 8);
                ushort4 o;
                o.x = f2bf(x.x); o.y = f2bf(x.y); o.z = f2bf(x.z); o.w = f2bf(x.w);
                *(ushort4*)&sfb[(size_t)row * 64 + i * 8 + p * 4] = o;
                r.x += x.x; r.y += x.y; r.z += x.z; r.w += x.w;   // strict per-j fold
            }
            float sp = (r.x + r.y) + (r.z + r.w);
            sp += __shfl_xor(sp, 1);                  // + other half (commutative: exact)
            if (p == 0) {
                spts4[row] = make_float4(spt[row * 3 + 0], spt[row * 3 + 1],
                                         spt[row * 3 + 2], sp > 0.0f ? 1.0f : -1.0f);
            }
        }
    } else if (b < 814) {
        const int e = (b - 782) * 256 + t;            // 0..8191
        const int lane = e & 63, s = (e >> 6) & 31, wq = e >> 11;
        const int d = wq * 16 + (lane & 15);
        const int lqp = lane >> 4;
        unsigned short o8[8];
#pragma unroll
        for (int j = 0; j < 8; j++) {
            const int kc = s * 32 + lqp * 8 + j;
            const int c = kc >> 4, k = kc & 15;
            o8[j] = (k < KK) ? f2bf(w[k * 4096 + c * 64 + d]) : (unsigned short)0;
        }
#pragma unroll
        for (int j = 0; j < 8; j++) wbf2[(size_t)e * 8 + j] = o8[j];
    } else {
        if (t < 16) *(ushort4*)&sfb[(size_t)NPTS * 64 + t * 4] = make_ushort4(0, 0, 0, 0);
        else if (t == 16) spts4[NPTS] = make_float4(1.0e6f, 1.0e6f, 1.0e6f, -1.0f);
        else if (t >= 32 && t < 32 + KK) {
            const int k = t - 32;
            const float kx = kpts[k * 3 + 0], ky = kpts[k * 3 + 1], kz = kpts[k * 3 + 2];
            kpp[k] = make_float4(-2.f * kx, -2.f * ky, -2.f * kz, kx * kx + ky * ky + kz * kz);
        }
    }
}

// =======================================================================
// Persistent fused kernel: 782 blocks x 4 tiles, software-pipelined.
// Per iteration: phaseC(t-1) runs while tile t's sfb gathers (issued last
// iteration, after phaseB freed the g regs) are in flight -> gather latency
// hidden under ~800 cy of MFMA + L2 stream instead of exposed.
// LDS: stage 20480 + wtw 32896 + inv 64 = 53440 B -> 3 blocks/CU.
// =======================================================================
__global__ __launch_bounds__(512, 6) void kpconv_fused(
    const float* __restrict__ q_points,
    const float4* __restrict__ spts4,         // (N+1) {x,y,z, oksign}, row N = (1e6..,-1)
    const unsigned short* __restrict__ sfb,   // (N+1,64) bf16, row N zero
    const int*   __restrict__ nbr,            // (M,32)
    const unsigned short* __restrict__ wbf2,  // lane-linear B frags (128 KB)
    const float4* __restrict__ kpp,           // (15) {-2kx,-2ky,-2kz,|kp|^2}
    float* __restrict__ out)                  // (M,64)
{
    const int t    = threadIdx.x;
    const int lane = t & 63;
    const int wv   = t >> 6;                  // 0..7
    const int l15  = lane & 15;
    const int lq   = lane >> 4;

    __shared__ __align__(16) unsigned short stage[8][64 * STPH];  // 20480 B
    __shared__ unsigned short wtw[TM * WTP];                      // 32896 B
    __shared__ float inv_lds[TM];

    const int mw = 2 * wv + (lane >> 5);
    const int h  = lane & 31;
    const int c4 = l15 * 4;

    // pipeline registers
    ushort4 g[2][8];
    float4 sp4;

    // phase-C constants (per-thread, tile-invariant)
    const int q  = wv & 3;
    const int kh = wv >> 2;
    const unsigned short* const ap = &wtw[l15 * WTP + kh * 512 + lq * 8];
    const unsigned short* const bp = wbf2 + ((size_t)((q * 32 + kh * 16) * 64) + lane) * 8;
    float* const scratch = (float*)&stage[0][0];

    // ---- PREFETCH(m0n): idxp/spts4 gather + 16 x 8B feature gathers into g ----
    auto PREFETCH = [&](const int m0n) {
        const int idxp = nbr[(size_t)(m0n + mw) * 32 + h];
#pragma unroll
        for (int mi = 0; mi < 2; mi++) {
            const int m = 2 * wv + mi;
#pragma unroll
            for (int g2 = 0; g2 < 4; g2++) {
                const int r0 = g2 * 8 + lq * 2;
                const int2 ip = *(const int2*)&nbr[(size_t)(m0n + m) * 32 + r0];
                const int i0 = min(ip.x, NPTS);
                const int i1 = min(ip.y, NPTS);
                g[mi][2 * g2]     = *(const ushort4*)&sfb[(size_t)i0 * 64 + c4];
                g[mi][2 * g2 + 1] = *(const ushort4*)&sfb[(size_t)i1 * 64 + c4];
            }
        }
        sp4 = spts4[min(idxp, NPTS)];
    };

    // ---- WEIGHTS(m0c): kernel-point weights + neighbor count ----
    auto WEIGHTS = [&](const int m0c) {
        const float rx = sp4.x - q_points[(m0c + mw) * 3 + 0];
        const float ry = sp4.y - q_points[(m0c + mw) * 3 + 1];
        const float rz = sp4.z - q_points[(m0c + mw) * 3 + 2];
        const float r2 = rx * rx + ry * ry + rz * rz;
        unsigned short* wrow = &wtw[mw * WTP];
#pragma unroll
        for (int k = 0; k < KK; k++) {
            const float4 kp = kpp[k];                 // wave-uniform -> s_load
            float d2 = kp.w;
            d2 = fmaf(rx, kp.x, d2);
            d2 = fmaf(ry, kp.y, d2);
            d2 = fmaf(rz, kp.z, d2);
            d2 = fmaxf(r2 + d2, 0.0f);                // guard tiny-negative from rounding
            const float wv_ = fmaxf(fmaf(-0.5f, __builtin_amdgcn_sqrtf(d2), 1.0f), 0.0f);
            wrow[k * STP + h] = f2bf(wv_);
        }
        wrow[15 * STP + h] = 0;                       // k-pad row

        const unsigned long long bal = __ballot(sp4.w > 0.0f);
        if (h == 0) {
            const int cnt = __popc((unsigned)(bal >> ((lane >> 5) * 32)));
            inv_lds[mw] = 1.0f / (float)(cnt < 1 ? 1 : cnt);
        }
    };

    // ---- PHASEB: transpose-stage g (half-h rounds) + weighted MFMAs -> wtw ----
    unsigned short* const st = stage[wv];
    const int swzh = (l15 >> 3) << 2;                 // flips slot bit2 for rows c >= 32
    const short8 zero8 = {0, 0, 0, 0, 0, 0, 0, 0};
    auto PHASEB = [&]() {
#pragma unroll
        for (int mi = 0; mi < 2; mi++) {
            const int m = 2 * wv + mi;
            const short8 afull = lds_load8(&wtw[m * WTP + l15 * STP + lq * 8]);
            floatx4 d[4];
#pragma unroll
            for (int ct = 0; ct < 4; ct++) d[ct] = (floatx4){0.f, 0.f, 0.f, 0.f};
#pragma unroll
            for (int r = 0; r < 2; r++) {
#pragma unroll
                for (int g2h = 0; g2h < 2; g2h++) {
                    const int g2 = 2 * r + g2h;
                    const int so = (((g2h * 4 + lq) ^ swzh)) * 2;
                    const ushort4 a = g[mi][2 * g2];
                    const ushort4 b = g[mi][2 * g2 + 1];
                    *(unsigned*)&st[(c4 + 0) * STPH + so] = (unsigned)a.x | ((unsigned)b.x << 16);
                    *(unsigned*)&st[(c4 + 1) * STPH + so] = (unsigned)a.y | ((unsigned)b.y << 16);
                    *(unsigned*)&st[(c4 + 2) * STPH + so] = (unsigned)a.z | ((unsigned)b.z << 16);
                    *(unsigned*)&st[(c4 + 3) * STPH + so] = (unsigned)a.w | ((unsigned)b.w << 16);
                }
                const short8 ar = ((lq >> 1) == r) ? afull : zero8;
#pragma unroll
                for (int ct = 0; ct < 4; ct++) {
                    const short8 bfrag =
                        lds_load8(&st[(ct * 16 + l15) * STPH + (((lq & 1) ^ (ct >> 1)) * 8)]);
                    d[ct] = __builtin_amdgcn_mfma_f32_16x16x32_bf16(ar, bfrag, d[ct], 0, 0, 0);
                }
            }
#pragma unroll
            for (int ct = 0; ct < 4; ct++) {
                ushort4 pk;                           // raw weighted (1/cnt in epilogue)
                pk.x = f2bf(d[ct][0]); pk.y = f2bf(d[ct][1]);
                pk.z = f2bf(d[ct][2]); pk.w = f2bf(d[ct][3]);
                *(ushort4*)&wtw[m * WTP + (ct * 16 + l15) * 16 + lq * 4] = pk;
            }
        }
    };

    // ---- PHASEC(m0p): out = inv * weighted x W'' (split-K over 2 wave-groups) ----
    auto PHASEC = [&](const int m0p) {
        floatx4 acc = {0.f, 0.f, 0.f, 0.f};
#pragma unroll 8
        for (int s = 0; s < 16; s++) {
            const short8 a = lds_load8(ap + s * 32);
            const short8 b = *(const short8*)(bp + s * 512);   // coalesced, L2-hot
            acc = __builtin_amdgcn_mfma_f32_16x16x32_bf16(a, b, acc, 0, 0, 0);
        }
        if (kh == 1) {
            *(floatx4*)&scratch[q * 256 + l15 * 16 + lq * 4] = acc;   // b128, uniform banks
        }
        __syncthreads();   // scratch partials visible
        if (kh == 0) {
            const floatx4 p = *(const floatx4*)&scratch[q * 256 + l15 * 16 + lq * 4];
            const int d = q * 16 + l15;
#pragma unroll
            for (int r = 0; r < 4; r++) {
                const int m = lq * 4 + r;
                out[(size_t)(m0p + m) * 64 + d] = (acc[r] + p[r]) * inv_lds[m];
            }
        }
    };

    // ======================= pipelined tile loop =======================
    const int tile0 = blockIdx.x * TPB;
    const int nt = min(TPB, NTILES - tile0);          // >= 1 for all blocks
    PREFETCH(tile0 * TM);
    int m0p = 0;
    for (int i = 0; i < nt; i++) {
        const int m0c = (tile0 + i) * TM;
        if (i > 0) PHASEC(m0p);                       // covers in-flight gathers of tile i
        __syncthreads();                              // wtw/inv free for new tile
        WEIGHTS(m0c);
        PHASEB();                                     // consumes g
        if (i + 1 < nt) PREFETCH(m0c + TM);           // issue next tile's gathers
        __syncthreads();                              // weighted rows + inv visible
        m0p = m0c;
    }
    PHASEC(m0p);                                      // epilogue tile
}

extern "C" void kernel_launch(void* const* d_in, const int* in_sizes, int n_in,
                              void* d_out, int out_size, void* d_ws, size_t ws_size,
                              hipStream_t stream) {
    const float* q_points = (const float*)d_in[0];
    const float* s_points = (const float*)d_in[1];
    const float* s_feats  = (const float*)d_in[2];
    const int*   nbr      = (const int*)d_in[3];
    const float* weights  = (const float*)d_in[4];
    const float* kpts     = (const float*)d_in[5];
    float* out = (float*)d_out;

    char* ws = (char*)d_ws;
    unsigned short* wbf2 = (unsigned short*)ws;              // [0, 131072)
    float4* spts4 = (float4*)(ws + 131072);                  // (N+1)*16 B = 1.6 MB
    float4* kpp = (float4*)(ws + 1731088);                   // 240 B, 16B-aligned
    unsigned short* sfb = (unsigned short*)(ws + 1731584);   // (N+1)*64 bf16 = 12.8 MB

    prep_all<<<815, 256, 0, stream>>>(s_feats, weights, kpts, s_points,
                                      sfb, spts4, wbf2, kpp);
    kpconv_fused<<<GRID, 512, 0, stream>>>(q_points, spts4, sfb, nbr,
                                           wbf2, kpp, out);
}

// Round 4
// 163.493 us; speedup vs baseline: 1.0964x; 1.0964x over previous
//
#include <hip/hip_runtime.h>
#include <hip/hip_bf16.h>

#define MPTS 50000
#define NPTS 100000
#define KK 15
#define TM 16      // queries per tile; 8 waves, wave owns 2 -> barrier-free A/B phases
#define NTILES (MPTS / TM)   // 3125
#define PGRID 512            // persistent grid: exactly 2 blocks/CU on 256 CUs
#define WTP 1028   // wtw row stride (shorts): 514 b32 = 2 mod 32 -> phase-C A reads uniform banks
#define STP 36     // stage + weight-row stride (shorts): 18 b32 -> all stage ops <=2-way

typedef __attribute__((ext_vector_type(8))) short short8;
typedef __attribute__((ext_vector_type(4))) short short4v;
typedef __attribute__((ext_vector_type(4))) float floatx4;

static __device__ __forceinline__ unsigned short f2bf(float f) {
    __hip_bfloat16 h = __float2bfloat16(f);
    return *reinterpret_cast<unsigned short*>(&h);
}

static __device__ __forceinline__ short8 lds_load8(const unsigned short* p) {
    const short4v a = *(const short4v*)p;
    const short4v b = *(const short4v*)(p + 4);
    short8 r;
    r[0] = a[0]; r[1] = a[1]; r[2] = a[2]; r[3] = a[3];
    r[4] = b[0]; r[5] = b[1]; r[6] = b[2]; r[7] = b[3];
    return r;
}

// ===================== single prep kernel (3 jobs by blockIdx range) ==================
// [0,782):   one pass over s_feats rows -> sfb (bf16) + rowsum-sign packed with xyz into spts4
// [782,814): wbf2 lane-linear B frags (128 KB)
// 814:       tail: zero sfb row N, spts4[N]=(1e6,1e6,1e6,-1), kpp
__global__ void prep_all(const float* __restrict__ sf, const float* __restrict__ w,
                         const float* __restrict__ kpts, const float* __restrict__ spt,
                         unsigned short* __restrict__ sfb, float4* __restrict__ spts4,
                         unsigned short* __restrict__ wbf2, float4* __restrict__ kpp) {
    const int b = blockIdx.x, t = threadIdx.x;
    if (b < 782) {
        const int tt = b * 256 + t;
        const int row = tt >> 1, p = tt & 1;          // lane p covers cols 4p+8i+0..3
        if (row < NPTS) {
            const float* base = sf + (size_t)row * 64 + p * 4;
            float4 r = *(const float4*)base;          // i = 0
            {
                ushort4 o;
                o.x = f2bf(r.x); o.y = f2bf(r.y); o.z = f2bf(r.z); o.w = f2bf(r.w);
                *(ushort4*)&sfb[(size_t)row * 64 + p * 4] = o;
            }
#pragma unroll
            for (int i = 1; i < 8; i++) {
                const float4 x = *(const float4*)(base + i * 8);
                ushort4 o;
                o.x = f2bf(x.x); o.y = f2bf(x.y); o.z = f2bf(x.z); o.w = f2bf(x.w);
                *(ushort4*)&sfb[(size_t)row * 64 + i * 8 + p * 4] = o;
                r.x += x.x; r.y += x.y; r.z += x.z; r.w += x.w;   // strict per-j fold
            }
            float sp = (r.x + r.y) + (r.z + r.w);
            sp += __shfl_xor(sp, 1);                  // + other half (commutative: exact)
            if (p == 0) {
                spts4[row] = make_float4(spt[row * 3 + 0], spt[row * 3 + 1],
                                         spt[row * 3 + 2], sp > 0.0f ? 1.0f : -1.0f);
            }
        }
    } else if (b < 814) {
        const int e = (b - 782) * 256 + t;            // 0..8191
        const int lane = e & 63, s = (e >> 6) & 31, wq = e >> 11;
        const int d = wq * 16 + (lane & 15);
        const int lqp = lane >> 4;
        unsigned short o8[8];
#pragma unroll
        for (int j = 0; j < 8; j++) {
            const int kc = s * 32 + lqp * 8 + j;
            const int c = kc >> 4, k = kc & 15;
            o8[j] = (k < KK) ? f2bf(w[k * 4096 + c * 64 + d]) : (unsigned short)0;
        }
#pragma unroll
        for (int j = 0; j < 8; j++) wbf2[(size_t)e * 8 + j] = o8[j];
    } else {
        if (t < 16) *(ushort4*)&sfb[(size_t)NPTS * 64 + t * 4] = make_ushort4(0, 0, 0, 0);
        else if (t == 16) spts4[NPTS] = make_float4(1.0e6f, 1.0e6f, 1.0e6f, -1.0f);
        else if (t >= 32 && t < 32 + KK) {
            const int k = t - 32;
            const float kx = kpts[k * 3 + 0], ky = kpts[k * 3 + 1], kz = kpts[k * 3 + 2];
            kpp[k] = make_float4(-2.f * kx, -2.f * ky, -2.f * kz, kx * kx + ky * ky + kz * kz);
        }
    }
}

// =======================================================================
// Persistent fused kernel: 512 blocks (2/CU), stride-looped tiles.
// W'' slice held in 64 VGPRs per wave, loaded ONCE -> phase-C global stream
// (400 MB of L2 re-reads) eliminated. Full-stage PHASEB (R1 form, 1 live acc)
// keeps VGPR <= 128. LDS: stage 36864 + wtw 32896 + inv 64 + scratch 4096
// = 73920 B -> 2 blocks/CU. Nothing is held in regs across PHASEC (no spill).
// Barriers/tile: 2. inv snapshotted to regs; scratch is dedicated (no alias).
// =======================================================================
__global__ __launch_bounds__(512, 4) void kpconv_fused(
    const float* __restrict__ q_points,
    const float4* __restrict__ spts4,         // (N+1) {x,y,z, oksign}, row N = (1e6..,-1)
    const unsigned short* __restrict__ sfb,   // (N+1,64) bf16, row N zero
    const int*   __restrict__ nbr,            // (M,32)
    const unsigned short* __restrict__ wbf2,  // lane-linear B frags (128 KB)
    const float4* __restrict__ kpp,           // (15) {-2kx,-2ky,-2kz,|kp|^2}
    float* __restrict__ out)                  // (M,64)
{
    const int t    = threadIdx.x;
    const int lane = t & 63;
    const int wv   = t >> 6;                  // 0..7
    const int l15  = lane & 15;
    const int lq   = lane >> 4;

    __shared__ __align__(16) unsigned short stage[8][64 * STP];   // 36864 B
    __shared__ unsigned short wtw[TM * WTP];                      // 32896 B
    __shared__ float inv_lds[TM];                                 // 64 B
    __shared__ __align__(16) float scratch[1024];                 // 4096 B (dedicated)

    const int mw = 2 * wv + (lane >> 5);
    const int h  = lane & 31;
    const int c4 = l15 * 4;

    // phase-C constants
    const int q  = wv & 3;
    const int kh = wv >> 2;
    const unsigned short* const ap = &wtw[l15 * WTP + kh * 512 + lq * 8];

    // ---- W'' slice -> registers, once per persistent block (16 frags = 64 VGPR) ----
    short8 wf[16];
    {
        const unsigned short* const bp =
            wbf2 + ((size_t)((q * 32 + kh * 16) * 64) + lane) * 8;
#pragma unroll
        for (int s = 0; s < 16; s++) wf[s] = *(const short8*)(bp + s * 512);
    }

    unsigned short* const st = stage[wv];
    const int swzw = (l15 >> 2) << 2;

    for (int tile = blockIdx.x; tile < NTILES; tile += PGRID) {
        const int m0 = tile * TM;

        // ---- PREFETCH: neighbor idx, point gather, 16 x 8B feature gathers ----
        const int idxp = nbr[(size_t)(m0 + mw) * 32 + h];
        const float4 sp4 = spts4[min(idxp, NPTS)];
        ushort4 g[2][8];
#pragma unroll
        for (int mi = 0; mi < 2; mi++) {
            const int m = 2 * wv + mi;
#pragma unroll
            for (int g2 = 0; g2 < 4; g2++) {
                const int r0 = g2 * 8 + lq * 2;
                const int2 ip = *(const int2*)&nbr[(size_t)(m0 + m) * 32 + r0];
                const int i0 = min(ip.x, NPTS);
                const int i1 = min(ip.y, NPTS);
                g[mi][2 * g2]     = *(const ushort4*)&sfb[(size_t)i0 * 64 + c4];
                g[mi][2 * g2 + 1] = *(const ushort4*)&sfb[(size_t)i1 * 64 + c4];
            }
        }

        // ---- WEIGHTS: kernel-point weights + neighbor count (covers gather latency) ----
        {
            const float rx = sp4.x - q_points[(m0 + mw) * 3 + 0];
            const float ry = sp4.y - q_points[(m0 + mw) * 3 + 1];
            const float rz = sp4.z - q_points[(m0 + mw) * 3 + 2];
            const float r2 = rx * rx + ry * ry + rz * rz;
            unsigned short* wrow = &wtw[mw * WTP];
#pragma unroll
            for (int k = 0; k < KK; k++) {
                const float4 kp = kpp[k];             // wave-uniform -> s_load
                float d2 = kp.w;
                d2 = fmaf(rx, kp.x, d2);
                d2 = fmaf(ry, kp.y, d2);
                d2 = fmaf(rz, kp.z, d2);
                d2 = fmaxf(r2 + d2, 0.0f);            // guard tiny-negative from rounding
                const float wv_ = fmaxf(fmaf(-0.5f, __builtin_amdgcn_sqrtf(d2), 1.0f), 0.0f);
                wrow[k * STP + h] = f2bf(wv_);
            }
            wrow[15 * STP + h] = 0;                   // k-pad row

            const unsigned long long bal = __ballot(sp4.w > 0.0f);
            if (h == 0) {
                const int cnt = __popc((unsigned)(bal >> ((lane >> 5) * 32)));
                inv_lds[mw] = 1.0f / (float)(cnt < 1 ? 1 : cnt);
            }
        }

        // ---- PHASEB: transpose-stage + weighted MFMAs -> wtw (full stage, 1 live acc) ----
#pragma unroll
        for (int mi = 0; mi < 2; mi++) {
            const int m = 2 * wv + mi;

            // transpose-write: b32 slot (g2*4+lq)^swz -> <=2-way banks
#pragma unroll
            for (int g2 = 0; g2 < 4; g2++) {
                const int so = ((g2 * 4 + lq) ^ swzw) * 2;
                const ushort4 a = g[mi][2 * g2];
                const ushort4 b = g[mi][2 * g2 + 1];
                *(unsigned*)&st[(c4 + 0) * STP + so] = (unsigned)a.x | ((unsigned)b.x << 16);
                *(unsigned*)&st[(c4 + 1) * STP + so] = (unsigned)a.y | ((unsigned)b.y << 16);
                *(unsigned*)&st[(c4 + 2) * STP + so] = (unsigned)a.z | ((unsigned)b.z << 16);
                *(unsigned*)&st[(c4 + 3) * STP + so] = (unsigned)a.w | ((unsigned)b.w << 16);
            }

            const short8 afrag = lds_load8(&wtw[m * WTP + l15 * STP + lq * 8]);
#pragma unroll
            for (int ct = 0; ct < 4; ct++) {
                const short8 bfrag = lds_load8(&st[(ct * 16 + l15) * STP + ((lq ^ ct) * 8)]);
                floatx4 d = {0.f, 0.f, 0.f, 0.f};
                d = __builtin_amdgcn_mfma_f32_16x16x32_bf16(afrag, bfrag, d, 0, 0, 0);
                ushort4 pk;                           // raw weighted (1/cnt in epilogue)
                pk.x = f2bf(d[0]); pk.y = f2bf(d[1]); pk.z = f2bf(d[2]); pk.w = f2bf(d[3]);
                *(ushort4*)&wtw[m * WTP + (ct * 16 + l15) * 16 + lq * 4] = pk;
            }
        }
        __syncthreads();   // barrier 1: weighted rows + inv visible

        // ---- PHASEC: out = inv * weighted x W'' (B from regs; split-K over kh) ----
        {
            float inv4[4];
            if (kh == 0) {
#pragma unroll
                for (int r = 0; r < 4; r++) inv4[r] = inv_lds[lq * 4 + r];  // snapshot
            }
            floatx4 acc = {0.f, 0.f, 0.f, 0.f};
#pragma unroll
            for (int s = 0; s < 16; s++) {
                const short8 a = lds_load8(ap + s * 32);
                acc = __builtin_amdgcn_mfma_f32_16x16x32_bf16(a, wf[s], acc, 0, 0, 0);
            }
            if (kh == 1) {
                *(floatx4*)&scratch[q * 256 + l15 * 16 + lq * 4] = acc;   // b128, uniform banks
            }
            __syncthreads();   // barrier 2: partials visible; wtw reads drained
            if (kh == 0) {
                const floatx4 p = *(const floatx4*)&scratch[q * 256 + l15 * 16 + lq * 4];
                const int d = q * 16 + l15;
#pragma unroll
                for (int r = 0; r < 4; r++) {
                    const int m = lq * 4 + r;
                    out[(size_t)(m0 + m) * 64 + d] = (acc[r] + p[r]) * inv4[r];
                }
            }
        }
    }
}

extern "C" void kernel_launch(void* const* d_in, const int* in_sizes, int n_in,
                              void* d_out, int out_size, void* d_ws, size_t ws_size,
                              hipStream_t stream) {
    const float* q_points = (const float*)d_in[0];
    const float* s_points = (const float*)d_in[1];
    const float* s_feats  = (const float*)d_in[2];
    const int*   nbr      = (const int*)d_in[3];
    const float* weights  = (const float*)d_in[4];
    const float* kpts     = (const float*)d_in[5];
    float* out = (float*)d_out;

    char* ws = (char*)d_ws;
    unsigned short* wbf2 = (unsigned short*)ws;              // [0, 131072)
    float4* spts4 = (float4*)(ws + 131072);                  // (N+1)*16 B = 1.6 MB
    float4* kpp = (float4*)(ws + 1731088);                   // 240 B, 16B-aligned
    unsigned short* sfb = (unsigned short*)(ws + 1731584);   // (N+1)*64 bf16 = 12.8 MB

    prep_all<<<815, 256, 0, stream>>>(s_feats, weights, kpts, s_points,
                                      sfb, spts4, wbf2, kpp);
    kpconv_fused<<<PGRID, 512, 0, stream>>>(q_points, spts4, sfb, nbr,
                                            wbf2, kpp, out);
}

// Round 5
// 148.366 us; speedup vs baseline: 1.2082x; 1.1020x over previous
//
#include <hip/hip_runtime.h>
#include <hip/hip_bf16.h>

#define MPTS 50000
#define NPTS 100000
#define KK 15
#define TM 16      // queries per tile; 8 waves, wave owns 2 -> barrier-free A/B phases
#define NTILES (MPTS / TM)   // 3125
#define PGRID 512            // persistent grid: 2 blocks/CU on 256 CUs (if VGPR<=128)
#define WTP 1028   // wtw row stride (shorts): 514 b32 = 2 mod 32 -> phase-C A reads uniform banks
#define STP 36     // stage + weight-row stride (shorts): 18 b32 -> all stage ops <=2-way

typedef __attribute__((ext_vector_type(8))) short short8;
typedef __attribute__((ext_vector_type(4))) short short4v;
typedef __attribute__((ext_vector_type(4))) float floatx4;

static __device__ __forceinline__ unsigned short f2bf(float f) {
    __hip_bfloat16 h = __float2bfloat16(f);
    return *reinterpret_cast<unsigned short*>(&h);
}

static __device__ __forceinline__ short8 lds_load8(const unsigned short* p) {
    const short4v a = *(const short4v*)p;
    const short4v b = *(const short4v*)(p + 4);
    short8 r;
    r[0] = a[0]; r[1] = a[1]; r[2] = a[2]; r[3] = a[3];
    r[4] = b[0]; r[5] = b[1]; r[6] = b[2]; r[7] = b[3];
    return r;
}

// ===================== single prep kernel (3 jobs by blockIdx range) ==================
__global__ void prep_all(const float* __restrict__ sf, const float* __restrict__ w,
                         const float* __restrict__ kpts, const float* __restrict__ spt,
                         unsigned short* __restrict__ sfb, float4* __restrict__ spts4,
                         unsigned short* __restrict__ wbf2, float4* __restrict__ kpp) {
    const int b = blockIdx.x, t = threadIdx.x;
    if (b < 782) {
        const int tt = b * 256 + t;
        const int row = tt >> 1, p = tt & 1;          // lane p covers cols 4p+8i+0..3
        if (row < NPTS) {
            const float* base = sf + (size_t)row * 64 + p * 4;
            float4 r = *(const float4*)base;          // i = 0
            {
                ushort4 o;
                o.x = f2bf(r.x); o.y = f2bf(r.y); o.z = f2bf(r.z); o.w = f2bf(r.w);
                *(ushort4*)&sfb[(size_t)row * 64 + p * 4] = o;
            }
#pragma unroll
            for (int i = 1; i < 8; i++) {
                const float4 x = *(const float4*)(base + i * 8);
                ushort4 o;
                o.x = f2bf(x.x); o.y = f2bf(x.y); o.z = f2bf(x.z); o.w = f2bf(x.w);
                *(ushort4*)&sfb[(size_t)row * 64 + i * 8 + p * 4] = o;
                r.x += x.x; r.y += x.y; r.z += x.z; r.w += x.w;   // strict per-j fold
            }
            float sp = (r.x + r.y) + (r.z + r.w);
            sp += __shfl_xor(sp, 1);                  // + other half (commutative: exact)
            if (p == 0) {
                spts4[row] = make_float4(spt[row * 3 + 0], spt[row * 3 + 1],
                                         spt[row * 3 + 2], sp > 0.0f ? 1.0f : -1.0f);
            }
        }
    } else if (b < 814) {
        const int e = (b - 782) * 256 + t;            // 0..8191
        const int lane = e & 63, s = (e >> 6) & 31, wq = e >> 11;
        const int d = wq * 16 + (lane & 15);
        const int lqp = lane >> 4;
        unsigned short o8[8];
#pragma unroll
        for (int j = 0; j < 8; j++) {
            const int kc = s * 32 + lqp * 8 + j;
            const int c = kc >> 4, k = kc & 15;
            o8[j] = (k < KK) ? f2bf(w[k * 4096 + c * 64 + d]) : (unsigned short)0;
        }
#pragma unroll
        for (int j = 0; j < 8; j++) wbf2[(size_t)e * 8 + j] = o8[j];
    } else {
        if (t < 16) *(ushort4*)&sfb[(size_t)NPTS * 64 + t * 4] = make_ushort4(0, 0, 0, 0);
        else if (t == 16) spts4[NPTS] = make_float4(1.0e6f, 1.0e6f, 1.0e6f, -1.0f);
        else if (t >= 32 && t < 32 + KK) {
            const int k = t - 32;
            const float kx = kpts[k * 3 + 0], ky = kpts[k * 3 + 1], kz = kpts[k * 3 + 2];
            kpp[k] = make_float4(-2.f * kx, -2.f * ky, -2.f * kz, kx * kx + ky * ky + kz * kz);
        }
    }
}

// gather one query's 8 row-pair fragments (8 x 8B random loads)
#define GATHER_M(mval)                                                          \
    do {                                                                        \
        const size_t nb_ = (size_t)(m0 + (mval)) * 32;                          \
        int2 ip_;                                                               \
        ip_ = *(const int2*)&nbr[nb_ + 0 + lq * 2];                             \
        g0 = *(const ushort4*)&sfb[(size_t)min(ip_.x, NPTS) * 64 + c4];         \
        g1 = *(const ushort4*)&sfb[(size_t)min(ip_.y, NPTS) * 64 + c4];         \
        ip_ = *(const int2*)&nbr[nb_ + 8 + lq * 2];                             \
        g2 = *(const ushort4*)&sfb[(size_t)min(ip_.x, NPTS) * 64 + c4];         \
        g3 = *(const ushort4*)&sfb[(size_t)min(ip_.y, NPTS) * 64 + c4];         \
        ip_ = *(const int2*)&nbr[nb_ + 16 + lq * 2];                            \
        g4 = *(const ushort4*)&sfb[(size_t)min(ip_.x, NPTS) * 64 + c4];         \
        g5 = *(const ushort4*)&sfb[(size_t)min(ip_.y, NPTS) * 64 + c4];         \
        ip_ = *(const int2*)&nbr[nb_ + 24 + lq * 2];                            \
        g6 = *(const ushort4*)&sfb[(size_t)min(ip_.x, NPTS) * 64 + c4];         \
        g7 = *(const ushort4*)&sfb[(size_t)min(ip_.y, NPTS) * 64 + c4];         \
    } while (0)

// transpose-write one row-pair into stage: b32 slot (g2v*4+lq)^swz -> <=2-way banks
#define STAGE_W(g2v, av, bv)                                                    \
    do {                                                                        \
        const int so_ = (((g2v) * 4 + lq) ^ swzw) * 2;                          \
        *(unsigned*)&st[(c4 + 0) * STP + so_] = (unsigned)(av).x | ((unsigned)(bv).x << 16); \
        *(unsigned*)&st[(c4 + 1) * STP + so_] = (unsigned)(av).y | ((unsigned)(bv).y << 16); \
        *(unsigned*)&st[(c4 + 2) * STP + so_] = (unsigned)(av).z | ((unsigned)(bv).z << 16); \
        *(unsigned*)&st[(c4 + 3) * STP + so_] = (unsigned)(av).w | ((unsigned)(bv).w << 16); \
    } while (0)

// 4 ct MFMAs for query m: weights(A) x staged feats(B) -> weighted rows in wtw
#define PHASEB_MFMA(mval)                                                       \
    do {                                                                        \
        const short8 afrag_ = lds_load8(&wtw[(mval) * WTP + l15 * STP + lq * 8]); \
        _Pragma("unroll")                                                       \
        for (int ct = 0; ct < 4; ct++) {                                        \
            const short8 bfrag_ = lds_load8(&st[(ct * 16 + l15) * STP + ((lq ^ ct) * 8)]); \
            floatx4 d_ = {0.f, 0.f, 0.f, 0.f};                                  \
            d_ = __builtin_amdgcn_mfma_f32_16x16x32_bf16(afrag_, bfrag_, d_, 0, 0, 0); \
            ushort4 pk_;                                                        \
            pk_.x = f2bf(d_[0]); pk_.y = f2bf(d_[1]);                           \
            pk_.z = f2bf(d_[2]); pk_.w = f2bf(d_[3]);                           \
            *(ushort4*)&wtw[(mval) * WTP + (ct * 16 + l15) * 16 + lq * 4] = pk_; \
        }                                                                       \
    } while (0)

// =======================================================================
// Persistent fused kernel: 512 blocks, stride-looped tiles.
// W'' slice in 16 NAMED short8 regs (64 VGPR), loaded once -> 400 MB/pass
// phase-C L2 stream becomes a 64 MB one-time load. Single-m gather prefetch
// (8 named ushort4 = 16 regs) keeps peak VGPR ~115 < 128 -> 2 blocks/CU.
// LDS: stage 36864 + wtw 32896 + inv 64 + scratch 4096 = 73920 B.
// =======================================================================
__global__ __launch_bounds__(512, 4) void kpconv_fused(
    const float* __restrict__ q_points,
    const float4* __restrict__ spts4,         // (N+1) {x,y,z, oksign}, row N = (1e6..,-1)
    const unsigned short* __restrict__ sfb,   // (N+1,64) bf16, row N zero
    const int*   __restrict__ nbr,            // (M,32)
    const unsigned short* __restrict__ wbf2,  // lane-linear B frags (128 KB)
    const float4* __restrict__ kpp,           // (15) {-2kx,-2ky,-2kz,|kp|^2}
    float* __restrict__ out)                  // (M,64)
{
    const int t    = threadIdx.x;
    const int lane = t & 63;
    const int wv   = t >> 6;                  // 0..7
    const int l15  = lane & 15;
    const int lq   = lane >> 4;

    __shared__ __align__(16) unsigned short stage[8][64 * STP];   // 36864 B
    __shared__ unsigned short wtw[TM * WTP];                      // 32896 B
    __shared__ float inv_lds[TM];                                 // 64 B
    __shared__ __align__(16) float scratch[1024];                 // 4096 B (dedicated)

    const int mw = 2 * wv + (lane >> 5);
    const int h  = lane & 31;
    const int c4 = l15 * 4;

    // phase-C constants
    const int q  = wv & 3;
    const int kh = wv >> 2;
    const unsigned short* const ap = &wtw[l15 * WTP + kh * 512 + lq * 8];

    // ---- W'' slice -> 16 NAMED registers, once per persistent block ----
    short8 wf0, wf1, wf2, wf3, wf4, wf5, wf6, wf7;
    short8 wf8, wf9, wf10, wf11, wf12, wf13, wf14, wf15;
    {
        const unsigned short* const bp =
            wbf2 + ((size_t)((q * 32 + kh * 16) * 64) + lane) * 8;
        wf0  = *(const short8*)(bp + 0 * 512);  wf1  = *(const short8*)(bp + 1 * 512);
        wf2  = *(const short8*)(bp + 2 * 512);  wf3  = *(const short8*)(bp + 3 * 512);
        wf4  = *(const short8*)(bp + 4 * 512);  wf5  = *(const short8*)(bp + 5 * 512);
        wf6  = *(const short8*)(bp + 6 * 512);  wf7  = *(const short8*)(bp + 7 * 512);
        wf8  = *(const short8*)(bp + 8 * 512);  wf9  = *(const short8*)(bp + 9 * 512);
        wf10 = *(const short8*)(bp + 10 * 512); wf11 = *(const short8*)(bp + 11 * 512);
        wf12 = *(const short8*)(bp + 12 * 512); wf13 = *(const short8*)(bp + 13 * 512);
        wf14 = *(const short8*)(bp + 14 * 512); wf15 = *(const short8*)(bp + 15 * 512);
    }

    unsigned short* const st = stage[wv];
    const int swzw = (l15 >> 2) << 2;

    for (int tile = blockIdx.x; tile < NTILES; tile += PGRID) {
        const int m0 = tile * TM;
        const int ma = 2 * wv, mb = 2 * wv + 1;

        // ---- PREFETCH: neighbor idx + point gather + query ma's features ----
        const int idxp = nbr[(size_t)(m0 + mw) * 32 + h];
        const float4 sp4 = spts4[min(idxp, NPTS)];
        ushort4 g0, g1, g2, g3, g4, g5, g6, g7;
        GATHER_M(ma);

        // ---- WEIGHTS: kernel-point weights + neighbor count (covers gather latency) ----
        {
            const float rx = sp4.x - q_points[(m0 + mw) * 3 + 0];
            const float ry = sp4.y - q_points[(m0 + mw) * 3 + 1];
            const float rz = sp4.z - q_points[(m0 + mw) * 3 + 2];
            const float r2 = rx * rx + ry * ry + rz * rz;
            unsigned short* wrow = &wtw[mw * WTP];
#pragma unroll
            for (int k = 0; k < KK; k++) {
                const float4 kp = kpp[k];             // wave-uniform -> s_load
                float d2 = kp.w;
                d2 = fmaf(rx, kp.x, d2);
                d2 = fmaf(ry, kp.y, d2);
                d2 = fmaf(rz, kp.z, d2);
                d2 = fmaxf(r2 + d2, 0.0f);            // guard tiny-negative from rounding
                const float wv_ = fmaxf(fmaf(-0.5f, __builtin_amdgcn_sqrtf(d2), 1.0f), 0.0f);
                wrow[k * STP + h] = f2bf(wv_);
            }
            wrow[15 * STP + h] = 0;                   // k-pad row

            const unsigned long long bal = __ballot(sp4.w > 0.0f);
            if (h == 0) {
                const int cnt = __popc((unsigned)(bal >> ((lane >> 5) * 32)));
                inv_lds[mw] = 1.0f / (float)(cnt < 1 ? 1 : cnt);
            }
        }

        // ---- PHASEB(ma): stage ma, issue mb gathers (latency under ma MFMAs), MFMA ma ----
        STAGE_W(0, g0, g1);
        STAGE_W(1, g2, g3);
        STAGE_W(2, g4, g5);
        STAGE_W(3, g6, g7);
        {
            ushort4 n0 = g0, n1 = g1;  (void)n0; (void)n1;   // (names reused below)
        }
        PHASEB_MFMA(ma);
        GATHER_M(mb);                                  // issued before mb staging needs them

        // ---- PHASEB(mb) ----
        STAGE_W(0, g0, g1);
        STAGE_W(1, g2, g3);
        STAGE_W(2, g4, g5);
        STAGE_W(3, g6, g7);
        PHASEB_MFMA(mb);

        __syncthreads();   // barrier 1: weighted rows + inv visible

        // ---- PHASEC: out = inv * weighted x W'' (B from named regs; split-K over kh) ----
        {
            float inv4[4];
            if (kh == 0) {
#pragma unroll
                for (int r = 0; r < 4; r++) inv4[r] = inv_lds[lq * 4 + r];  // snapshot
            }
            floatx4 acc = {0.f, 0.f, 0.f, 0.f};
            acc = __builtin_amdgcn_mfma_f32_16x16x32_bf16(lds_load8(ap + 0 * 32),  wf0,  acc, 0, 0, 0);
            acc = __builtin_amdgcn_mfma_f32_16x16x32_bf16(lds_load8(ap + 1 * 32),  wf1,  acc, 0, 0, 0);
            acc = __builtin_amdgcn_mfma_f32_16x16x32_bf16(lds_load8(ap + 2 * 32),  wf2,  acc, 0, 0, 0);
            acc = __builtin_amdgcn_mfma_f32_16x16x32_bf16(lds_load8(ap + 3 * 32),  wf3,  acc, 0, 0, 0);
            acc = __builtin_amdgcn_mfma_f32_16x16x32_bf16(lds_load8(ap + 4 * 32),  wf4,  acc, 0, 0, 0);
            acc = __builtin_amdgcn_mfma_f32_16x16x32_bf16(lds_load8(ap + 5 * 32),  wf5,  acc, 0, 0, 0);
            acc = __builtin_amdgcn_mfma_f32_16x16x32_bf16(lds_load8(ap + 6 * 32),  wf6,  acc, 0, 0, 0);
            acc = __builtin_amdgcn_mfma_f32_16x16x32_bf16(lds_load8(ap + 7 * 32),  wf7,  acc, 0, 0, 0);
            acc = __builtin_amdgcn_mfma_f32_16x16x32_bf16(lds_load8(ap + 8 * 32),  wf8,  acc, 0, 0, 0);
            acc = __builtin_amdgcn_mfma_f32_16x16x32_bf16(lds_load8(ap + 9 * 32),  wf9,  acc, 0, 0, 0);
            acc = __builtin_amdgcn_mfma_f32_16x16x32_bf16(lds_load8(ap + 10 * 32), wf10, acc, 0, 0, 0);
            acc = __builtin_amdgcn_mfma_f32_16x16x32_bf16(lds_load8(ap + 11 * 32), wf11, acc, 0, 0, 0);
            acc = __builtin_amdgcn_mfma_f32_16x16x32_bf16(lds_load8(ap + 12 * 32), wf12, acc, 0, 0, 0);
            acc = __builtin_amdgcn_mfma_f32_16x16x32_bf16(lds_load8(ap + 13 * 32), wf13, acc, 0, 0, 0);
            acc = __builtin_amdgcn_mfma_f32_16x16x32_bf16(lds_load8(ap + 14 * 32), wf14, acc, 0, 0, 0);
            acc = __builtin_amdgcn_mfma_f32_16x16x32_bf16(lds_load8(ap + 15 * 32), wf15, acc, 0, 0, 0);

            if (kh == 1) {
                *(floatx4*)&scratch[q * 256 + l15 * 16 + lq * 4] = acc;   // b128, uniform banks
            }
            __syncthreads();   // barrier 2: partials visible; wtw reads drained
            if (kh == 0) {
                const floatx4 p = *(const floatx4*)&scratch[q * 256 + l15 * 16 + lq * 4];
                const int d = q * 16 + l15;
#pragma unroll
                for (int r = 0; r < 4; r++) {
                    const int m = lq * 4 + r;
                    out[(size_t)(m0 + m) * 64 + d] = (acc[r] + p[r]) * inv4[r];
                }
            }
        }
    }
}

extern "C" void kernel_launch(void* const* d_in, const int* in_sizes, int n_in,
                              void* d_out, int out_size, void* d_ws, size_t ws_size,
                              hipStream_t stream) {
    const float* q_points = (const float*)d_in[0];
    const float* s_points = (const float*)d_in[1];
    const float* s_feats  = (const float*)d_in[2];
    const int*   nbr      = (const int*)d_in[3];
    const float* weights  = (const float*)d_in[4];
    const float* kpts     = (const float*)d_in[5];
    float* out = (float*)d_out;

    char* ws = (char*)d_ws;
    unsigned short* wbf2 = (unsigned short*)ws;              // [0, 131072)
    float4* spts4 = (float4*)(ws + 131072);                  // (N+1)*16 B = 1.6 MB
    float4* kpp = (float4*)(ws + 1731088);                   // 240 B, 16B-aligned
    unsigned short* sfb = (unsigned short*)(ws + 1731584);   // (N+1)*64 bf16 = 12.8 MB

    prep_all<<<815, 256, 0, stream>>>(s_feats, weights, kpts, s_points,
                                      sfb, spts4, wbf2, kpp);
    kpconv_fused<<<PGRID, 512, 0, stream>>>(q_points, spts4, sfb, nbr,
                                            wbf2, kpp, out);
}